// Round 1
// baseline (647.463 us; speedup 1.0000x reference)
//
#include <hip/hip_runtime.h>

#define H 128
#define MAXLEN 431
#define BB 2048
#define NBLK 1724
#define NWAVES (NBLK * 4)          // 6896 waves
#define NP (MAXLEN * BB / 32)      // 27584 pairs; 27584/6896 = exactly 4 iters/wave

__device__ __forceinline__ float dot4(float4 a, float4 b) {
    return a.x * b.x + a.y * b.y + a.z * b.z + a.w * b.w;
}

// Fully fused, ZERO workspace use. Each block redundantly computes
// u1/u2/c (LDS) and the 16 hdot spans (32 rows each) that its 4 waves
// will consume, then runs the same 16KB-per-iteration streaming loop
// as the previous main_scores.
//
// LDS: u1s(512B) + u2s(512B) + hd(2KB) + cs = ~3.1 KB -> no occupancy impact.
__global__ __launch_bounds__(256) void fused(const float* __restrict__ k_emb,
                                             const float* __restrict__ hidden,
                                             const float* __restrict__ attn_w,
                                             const float* __restrict__ attn_b,
                                             const float* __restrict__ v,
                                             float* __restrict__ out) {
    __shared__ float u1s[H];
    __shared__ float u2s[H];
    __shared__ float hd[16][32];   // hd[s][j]: s = wave*4 + k-iter, j = row-in-span
    __shared__ float cs;

    const int t = threadIdx.x;

    // Phase A: u1 (waves 0-1), u2 (waves 2-3), c (thread 0). attn_w is
    // 128KB and L2/L3-hot after the first blocks touch it.
    if (t < 128) {
        float acc = 0.f;
        #pragma unroll 8
        for (int e = 0; e < H; ++e) acc += v[e] * attn_w[e * 2 * H + t];
        u1s[t] = acc;
    } else {
        const int h = t - 128;
        float acc = 0.f;
        #pragma unroll 8
        for (int e = 0; e < H; ++e) acc += v[e] * attn_w[e * 2 * H + H + h];
        u2s[h] = acc;
    }
    if (t == 0) {
        float c = 0.f;
        for (int e = 0; e < H; ++e) c += attn_b[e] * v[e];
        cs = c;
    }
    __syncthreads();

    // Phase B: the 512 hdot values this block needs (16 spans x 32 rows),
    // 2 per thread. hidden is 1MB -> L2-resident per XCD.
    {
        const float4* u14 = (const float4*)u1s;
        const float cc = cs;
        #pragma unroll
        for (int q = 0; q < 2; ++q) {
            const int idx = t + q * 256;
            const int s = idx >> 5, j = idx & 31;
            const int p = blockIdx.x * 4 + (s >> 2) + NWAVES * (s & 3);
            const int b = (32 * p + j) & (BB - 1);
            const float4* h4 = (const float4*)hidden + b * (H / 4);
            float a = 0.f;
            #pragma unroll
            for (int jj = 0; jj < H / 4; ++jj) a += dot4(h4[jj], u14[jj]);
            hd[s][j] = a + cc;
        }
    }
    __syncthreads();

    // Phase C: identical streaming structure to the previous main_scores.
    // lane = rk*8 + oct; lane owns one 64B line of row (16g + rk [+8]),
    // wave covers a contiguous pair of 8KB groups (16KB) per iteration.
    const int lane = t & 63;
    const int oct  = lane & 7;
    const int rk   = lane >> 3;
    const int w    = t >> 6;

    const float4* u2p = (const float4*)u2s + oct * 4;
    const float4 U0 = u2p[0], U1 = u2p[1], U2 = u2p[2], U3 = u2p[3];

    const int wid = blockIdx.x * 4 + w;

    #pragma unroll 1   // keep VGPR pressure/occupancy of the rolled loop
    for (int k = 0; k < 4; ++k) {
        const int p  = wid + NWAVES * k;   // < NP, no tail
        const int g0 = p * 2;
        const int s  = w * 4 + k;
        const int rowA0 = g0 * 16 + rk;

        // hdot from LDS (broadcast across the oct group, conflict-free)
        float hA0 = hd[s][rk],      hB0 = hd[s][rk + 8];
        float hA1 = hd[s][rk + 16], hB1 = hd[s][rk + 24];

        const float4* base = (const float4*)k_emb + (long long)g0 * 512 + rk * 32 + oct * 4;
        float4 a0 = base[0],   a1 = base[1],   a2 = base[2],   a3 = base[3];
        float4 c0 = base[256], c1 = base[257], c2 = base[258], c3 = base[259];
        float4 d0 = base[512], d1 = base[513], d2 = base[514], d3 = base[515];
        float4 e0 = base[768], e1 = base[769], e2 = base[770], e3 = base[771];

        float pa = dot4(a0, U0) + dot4(a1, U1) + dot4(a2, U2) + dot4(a3, U3);
        float pb = dot4(c0, U0) + dot4(c1, U1) + dot4(c2, U2) + dot4(c3, U3);
        float pc = dot4(d0, U0) + dot4(d1, U1) + dot4(d2, U2) + dot4(d3, U3);
        float pd = dot4(e0, U0) + dot4(e1, U1) + dot4(e2, U2) + dot4(e3, U3);

        #pragma unroll
        for (int off = 1; off <= 4; off <<= 1) {
            pa += __shfl_xor(pa, off);
            pb += __shfl_xor(pb, off);
            pc += __shfl_xor(pc, off);
            pd += __shfl_xor(pd, off);
        }

        if (oct == 0) {
            const int bA0 = rowA0 & (BB - 1),        bB0 = (rowA0 + 8) & (BB - 1);
            const int bA1 = (rowA0 + 16) & (BB - 1), bB1 = (rowA0 + 24) & (BB - 1);
            out[bA0 * MAXLEN + (rowA0 >> 11)]        = pa + hA0;
            out[bB0 * MAXLEN + ((rowA0 + 8) >> 11)]  = pb + hB0;
            out[bA1 * MAXLEN + ((rowA0 + 16) >> 11)] = pc + hA1;
            out[bB1 * MAXLEN + ((rowA0 + 24) >> 11)] = pd + hB1;
        }
    }
}

extern "C" void kernel_launch(void* const* d_in, const int* in_sizes, int n_in,
                              void* d_out, int out_size, void* d_ws, size_t ws_size,
                              hipStream_t stream) {
    const float* hidden = (const float*)d_in[0];   // (1, 2048, 128)
    const float* k_emb  = (const float*)d_in[1];   // (431, 2048, 128)
    const float* attn_w = (const float*)d_in[2];   // (128, 256)
    const float* attn_b = (const float*)d_in[3];   // (128,)
    const float* v      = (const float*)d_in[4];   // (1, 128)
    float* out = (float*)d_out;                    // (2048, 431)
    (void)in_sizes; (void)n_in; (void)out_size;
    (void)d_ws; (void)ws_size;                     // workspace intentionally unused

    fused<<<NBLK, 256, 0, stream>>>(k_emb, hidden, attn_w, attn_b, v, out);
}

// Round 2
// 600.766 us; speedup vs baseline: 1.0777x; 1.0777x over previous
//
#include <hip/hip_runtime.h>

#define H 128
#define MAXLEN 431
#define BB 2048

// ws layout (floats): [0..127]=u2, [384..2431]=hdot[b] (h.u1 + c folded in)

__device__ __forceinline__ float dot4(float4 a, float4 b) {
    return a.x * b.x + a.y * b.y + a.z * b.z + a.w * b.w;
}

// One fused prep kernel, 8 blocks x 256 threads.
// Each block redundantly computes u1 into LDS (waves 0-1) while waves 2-3
// compute u2 (block 0 stores it to ws). Then each block produces 256 hdots.
__global__ void prep(const float* __restrict__ attn_w,
                     const float* __restrict__ attn_b,
                     const float* __restrict__ v,
                     const float* __restrict__ hidden,
                     float* __restrict__ ws) {
    __shared__ float u1s[H];
    __shared__ float cs;
    const int t = threadIdx.x;

    if (t < 128) {                       // waves 0-1: u1 column t
        float acc = 0.f;
        for (int e = 0; e < H; ++e) acc += v[e] * attn_w[e * 2 * H + t];
        u1s[t] = acc;
    } else {                             // waves 2-3: u2 column t-128
        int h = t - 128;
        float acc = 0.f;
        for (int e = 0; e < H; ++e) acc += v[e] * attn_w[e * 2 * H + H + h];
        if (blockIdx.x == 0) ws[h] = acc;
    }
    if (t == 0) {
        float c = 0.f;
        for (int e = 0; e < H; ++e) c += attn_b[e] * v[e];
        cs = c;
    }
    __syncthreads();

    const int b = blockIdx.x * 256 + t;          // 8*256 = 2048
    const float4* h4  = (const float4*)hidden + b * (H / 4);
    const float4* u14 = (const float4*)u1s;
    float a = 0.f;
    #pragma unroll
    for (int j = 0; j < H / 4; ++j) a += dot4(h4[j], u14[j]);
    ws[384 + b] = a + cs;
}

// Lane layout: lane = rk*8 + oct. Lane owns one 64B line (16 floats) of row
// (16g + rk [+8]), read as 4 back-to-back float4 loads. Per iteration a wave
// covers a contiguous PAIR of 8KB groups (16 KB, 16 dwordx4 in flight).
// Per-row reduce = 3-step shfl_xor within the 8-lane oct group.
__global__ void main_scores(const float* __restrict__ k_emb,
                            const float* __restrict__ ws,
                            float* __restrict__ out) {
    const int lane = threadIdx.x & 63;
    const int oct  = lane & 7;
    const int rk   = lane >> 3;

    const float4* u2p = (const float4*)ws + oct * 4;
    const float4 u0 = u2p[0], u1 = u2p[1], u2 = u2p[2], u3 = u2p[3];
    const float* hdot = ws + 384;

    const int wid = blockIdx.x * (blockDim.x >> 6) + (threadIdx.x >> 6);
    const int nw  = gridDim.x * (blockDim.x >> 6);          // 6896
    const int NP  = MAXLEN * BB / 32;                       // 27584 pairs

    for (int p = wid; p < NP; p += nw) {                    // exactly 4 iters
        const int g0 = p * 2;
        // hoist L2-hot hdot loads so latency overlaps the HBM loads
        const int rowA0 = g0 * 16 + rk;
        const int bA0 = rowA0 & (BB - 1),        bB0 = (rowA0 + 8) & (BB - 1);
        const int bA1 = (rowA0 + 16) & (BB - 1), bB1 = (rowA0 + 24) & (BB - 1);
        float hA0 = hdot[bA0], hB0 = hdot[bB0];
        float hA1 = hdot[bA1], hB1 = hdot[bB1];

        const float4* base = (const float4*)k_emb + (long long)g0 * 512 + rk * 32 + oct * 4;
        float4 a0 = base[0],   a1 = base[1],   a2 = base[2],   a3 = base[3];
        float4 c0 = base[256], c1 = base[257], c2 = base[258], c3 = base[259];
        float4 d0 = base[512], d1 = base[513], d2 = base[514], d3 = base[515];
        float4 e0 = base[768], e1 = base[769], e2 = base[770], e3 = base[771];

        float pa = dot4(a0,u0) + dot4(a1,u1) + dot4(a2,u2) + dot4(a3,u3);
        float pb = dot4(c0,u0) + dot4(c1,u1) + dot4(c2,u2) + dot4(c3,u3);
        float pc = dot4(d0,u0) + dot4(d1,u1) + dot4(d2,u2) + dot4(d3,u3);
        float pd = dot4(e0,u0) + dot4(e1,u1) + dot4(e2,u2) + dot4(e3,u3);

        #pragma unroll
        for (int off = 1; off <= 4; off <<= 1) {
            pa += __shfl_xor(pa, off);
            pb += __shfl_xor(pb, off);
            pc += __shfl_xor(pc, off);
            pd += __shfl_xor(pd, off);
        }

        if (oct == 0) {
            const int lA0 = rowA0 >> 11;
            const int lB0 = (rowA0 + 8) >> 11;
            const int lA1 = (rowA0 + 16) >> 11;
            const int lB1 = (rowA0 + 24) >> 11;
            out[bA0 * MAXLEN + lA0] = pa + hA0;
            out[bB0 * MAXLEN + lB0] = pb + hB0;
            out[bA1 * MAXLEN + lA1] = pc + hA1;
            out[bB1 * MAXLEN + lB1] = pd + hB1;
        }
    }
}

extern "C" void kernel_launch(void* const* d_in, const int* in_sizes, int n_in,
                              void* d_out, int out_size, void* d_ws, size_t ws_size,
                              hipStream_t stream) {
    const float* hidden = (const float*)d_in[0];   // (1, 2048, 128)
    const float* k_emb  = (const float*)d_in[1];   // (431, 2048, 128)
    const float* attn_w = (const float*)d_in[2];   // (128, 256)
    const float* attn_b = (const float*)d_in[3];   // (128,)
    const float* v      = (const float*)d_in[4];   // (1, 128)
    float* out = (float*)d_out;                    // (2048, 431)
    float* ws  = (float*)d_ws;

    prep<<<8, 256, 0, stream>>>(attn_w, attn_b, v, hidden, ws);
    // 1724 blocks * 4 waves = 6896 waves; 27584 pairs / 6896 = exactly 4
    // iterations of 16 KB per wave, all waves co-resident, no tail.
    main_scores<<<1724, 256, 0, stream>>>(k_emb, ws, out);
}